// Round 3
// baseline (458.183 us; speedup 1.0000x reference)
//
#include <hip/hip_runtime.h>
#include <math.h>

constexpr int IMH = 2048, IMW = 2048, NB = 4;
constexpr int NPIX = NB * IMH * IMW;           // 16777216
constexpr unsigned KSEL = 8388607u;            // floor(0.5*(NPIX-1)) -> quantile 'lower'

// ---------- helpers ----------
__device__ __forceinline__ unsigned f2u(float f) {
    unsigned b = __float_as_uint(f);
    return (b & 0x80000000u) ? ~b : (b | 0x80000000u);   // monotone float->uint
}

__device__ __forceinline__ void gauss7(float* a) {
    const double g0 = 0.8352702114112720;   // exp(-0.18)
    const double g1 = 0.9231163463866358;   // exp(-0.08)
    const double g2 = 0.9801986733067553;   // exp(-0.02)
    const double s = 2.0 * (g0 + g1 + g2) + 1.0;
    const double inv = 1.0 / s;
    a[0] = a[6] = (float)(g0 * inv);
    a[1] = a[5] = (float)(g1 * inv);
    a[2] = a[4] = (float)(g2 * inv);
    a[3] = (float)inv;
}

__device__ __forceinline__ void sobel_at(const float* p, int stride, float& ix, float& iy) {
    float x00 = p[0], x01 = p[1], x02 = p[2];
    float x10 = p[stride], x12 = p[stride + 2];
    float x20 = p[2 * stride], x21 = p[2 * stride + 1], x22 = p[2 * stride + 2];
    ix = (x02 + 2.0f * x12 + x22) - (x00 + 2.0f * x10 + x20);
    iy = (x20 + 2.0f * x21 + x22) - (x00 + 2.0f * x01 + x02);
}

// ---------- K1: Sobel + products + separable 7x7 Gaussian + R + hist1 ----------
// tile 64x16. LDS floats: [0,4224) STH 3 planes 22x64 (aliases SX 24x76 and 4096-bin hist)
//                         [4224,7392) SIXY 22 rows of 72 float2
__launch_bounds__(256, 5)
__global__ void harris_R(const float* __restrict__ x, float* __restrict__ Rout,
                         unsigned* __restrict__ hist) {
    __shared__ float smem[7392];   // 29568 B -> 5 blocks/CU
    float* STH = smem;             // plane p at p*1408, row stride 64
    float* SX = smem;              // 24x76
    float* SIXY = smem + 4224;     // float2 rows, stride 72 f2 (144 f)
    unsigned* LH = (unsigned*)smem;

    const int tid = threadIdx.x;
    const int tx = tid & 63, ty = tid >> 6;
    const int x0 = blockIdx.x * 64, y0 = blockIdx.y * 16, b = blockIdx.z;
    const float* xb = x + (size_t)b * IMH * IMW;
    const bool interior = (x0 >= 4) && (x0 + 72 <= IMW) && (y0 >= 4) && (y0 + 20 <= IMH);

    // ---- load x tile 24x76 (rows y0-4..y0+19, cols x0-4..x0+71) ----
    if (interior) {
        const float* xb0 = xb + (size_t)(y0 - 4) * IMW + (x0 - 4);
        #pragma unroll
        for (int k = 0; k < 6; ++k) {
            int r = ty + 4 * k;
            SX[r * 76 + tx] = xb0[(size_t)r * IMW + tx];
        }
        for (int i = tid; i < 288; i += 256) {
            int r = i / 12, c = 64 + (i - r * 12);
            SX[r * 76 + c] = xb0[(size_t)r * IMW + c];
        }
    } else {
        for (int i = tid; i < 24 * 76; i += 256) {
            int r = i / 76, c = i - r * 76;
            int gy = y0 - 4 + r, gx = x0 - 4 + c;
            float v = 0.0f;
            if ((unsigned)gy < (unsigned)IMH && (unsigned)gx < (unsigned)IMW)
                v = xb[(size_t)gy * IMW + gx];
            SX[r * 76 + c] = v;
        }
    }
    __syncthreads();

    // ---- Sobel 22 rows x 72 cols -> SIXY (zero outside image) ----
    float2* SI2 = (float2*)SIXY;
    if (interior) {
        #pragma unroll
        for (int k = 0; k < 6; ++k) {
            int r = ty + 4 * k;
            if (r < 22) {
                float ix, iy;
                sobel_at(SX + r * 76 + tx, 76, ix, iy);
                SI2[r * 72 + tx] = make_float2(ix, iy);
            }
        }
        if (tid < 176) {
            int r = tid >> 3, c = 64 + (tid & 7);
            float ix, iy;
            sobel_at(SX + r * 76 + c, 76, ix, iy);
            SI2[r * 72 + c] = make_float2(ix, iy);
        }
    } else {
        for (int i = tid; i < 22 * 72; i += 256) {
            int r = i / 72, c = i - r * 72;
            int gy = y0 - 3 + r, gx = x0 - 3 + c;
            float ix = 0.0f, iy = 0.0f;
            if ((unsigned)gy < (unsigned)IMH && (unsigned)gx < (unsigned)IMW)
                sobel_at(SX + r * 76 + c, 76, ix, iy);
            SI2[r * 72 + c] = make_float2(ix, iy);
        }
    }
    __syncthreads();

    float a[7]; gauss7(a);

    // ---- h-blur of products (fused), 22 rows x 64 cols -> 3 planar STH ----
    #pragma unroll
    for (int k = 0; k < 6; ++k) {
        int r = ty + 4 * k;
        if (r < 22) {
            const float2* p = (const float2*)(SIXY + r * 144) + tx;
            float sxx = 0.f, syy = 0.f, sxy = 0.f;
            #pragma unroll
            for (int d = 0; d < 7; ++d) {
                float2 v = p[d];
                float t = a[d] * v.x;
                sxx += t * v.x;
                sxy += t * v.y;
                syy += (a[d] * v.y) * v.y;
            }
            STH[r * 64 + tx] = sxx;
            STH[1408 + r * 64 + tx] = syy;
            STH[2816 + r * 64 + tx] = sxy;
        }
    }
    __syncthreads();

    // ---- v-blur with register sliding window: 4 consecutive rows/thread ----
    float vxx[10], vyy[10], vxy[10];
    {
        const float* base = STH + (4 * ty) * 64 + tx;
        #pragma unroll
        for (int t = 0; t < 10; ++t) {
            vxx[t] = base[t * 64];
            vyy[t] = base[1408 + t * 64];
            vxy[t] = base[2816 + t * 64];
        }
    }
    float rv[4];
    float* Rb = Rout + (size_t)b * IMH * IMW + (size_t)y0 * IMW + x0;
    #pragma unroll
    for (int j = 0; j < 4; ++j) {
        float sxx = 0.f, syy = 0.f, sxy = 0.f;
        #pragma unroll
        for (int d = 0; d < 7; ++d) {
            sxx += a[d] * vxx[j + d];
            syy += a[d] * vyy[j + d];
            sxy += a[d] * vxy[j + d];
        }
        float tr = sxx + syy;
        float R = sxx * syy - sxy * sxy - 0.05f * tr * tr;
        rv[j] = R;
        Rb[(size_t)(4 * ty + j) * IMW + tx] = R;
    }
    __syncthreads();   // all STH reads done; LH may now overwrite

    for (int i = tid; i < 4096; i += 256) LH[i] = 0u;
    __syncthreads();
    #pragma unroll
    for (int j = 0; j < 4; ++j) atomicAdd(&LH[f2u(rv[j]) >> 20], 1u);
    __syncthreads();
    const unsigned slot = ((blockIdx.z * gridDim.y + blockIdx.y) * gridDim.x + blockIdx.x) & 7u;
    for (int i = tid; i < 4096; i += 256) {
        unsigned c = LH[i];
        if (c) atomicAdd(&hist[i * 8 + slot], c);
    }
}

// ---------- median: radix select; pass 1 fused above (8-slot striped) ----------
__global__ void zero_kernel(unsigned* __restrict__ p, int n, int kidx, unsigned kval) {
    int i = blockIdx.x * blockDim.x + threadIdx.x;
    if (i < n) p[i] = (i == kidx) ? kval : 0u;
}

__global__ void hist2_kernel(const float* __restrict__ R, unsigned* __restrict__ hist,
                             const unsigned* __restrict__ sel) {
    __shared__ unsigned lh[4096];
    for (int i = threadIdx.x; i < 4096; i += 256) lh[i] = 0u;
    __syncthreads();
    const unsigned pref = sel[1];
    const float4* R4 = (const float4*)R;
    const int n4 = NPIX / 4;
    for (int i = blockIdx.x * 256 + threadIdx.x; i < n4; i += gridDim.x * 256) {
        float4 v = R4[i];
        unsigned u;
        u = f2u(v.x); if ((u >> 20) == pref) atomicAdd(&lh[(u >> 8) & 0xFFFu], 1u);
        u = f2u(v.y); if ((u >> 20) == pref) atomicAdd(&lh[(u >> 8) & 0xFFFu], 1u);
        u = f2u(v.z); if ((u >> 20) == pref) atomicAdd(&lh[(u >> 8) & 0xFFFu], 1u);
        u = f2u(v.w); if ((u >> 20) == pref) atomicAdd(&lh[(u >> 8) & 0xFFFu], 1u);
    }
    __syncthreads();
    for (int i = threadIdx.x; i < 4096; i += 256) { unsigned c = lh[i]; if (c) atomicAdd(&hist[i], c); }
}

__global__ void hist3_kernel(const float* __restrict__ R, unsigned* __restrict__ hist,
                             const unsigned* __restrict__ sel) {
    __shared__ unsigned lh[256];
    if (threadIdx.x < 256) lh[threadIdx.x] = 0u;
    __syncthreads();
    const unsigned pref = sel[1];
    const float4* R4 = (const float4*)R;
    const int n4 = NPIX / 4;
    for (int i = blockIdx.x * 256 + threadIdx.x; i < n4; i += gridDim.x * 256) {
        float4 v = R4[i];
        unsigned u;
        u = f2u(v.x); if ((u >> 8) == pref) atomicAdd(&lh[u & 0xFFu], 1u);
        u = f2u(v.y); if ((u >> 8) == pref) atomicAdd(&lh[u & 0xFFu], 1u);
        u = f2u(v.z); if ((u >> 8) == pref) atomicAdd(&lh[u & 0xFFu], 1u);
        u = f2u(v.w); if ((u >> 8) == pref) atomicAdd(&lh[u & 0xFFu], 1u);
    }
    __syncthreads();
    { unsigned c = lh[threadIdx.x]; if (c) atomicAdd(&hist[threadIdx.x], c); }
}

// sel[0]=k_remaining, sel[1]=prefix; sel[2] (as float) = median once final
__global__ void select_kernel(const unsigned* __restrict__ hist, unsigned* __restrict__ sel,
                              int bpt, int bits, int final_stage, int slots) {
    __shared__ unsigned part[256];
    __shared__ unsigned grp[16];
    __shared__ int chs;
    __shared__ unsigned runs;
    const int t = threadIdx.x;
    const unsigned krem = sel[0];
    unsigned s = 0;
    for (int i = 0; i < bpt; ++i) {
        unsigned bsum = 0;
        for (int j = 0; j < slots; ++j) bsum += hist[(t * bpt + i) * slots + j];
        s += bsum;
    }
    part[t] = s;
    __syncthreads();
    #pragma unroll
    for (int off = 1; off < 256; off <<= 1) {
        unsigned add = (t >= off) ? part[t - off] : 0u;
        __syncthreads();
        part[t] += add;
        __syncthreads();
    }
    unsigned incl = part[t];
    unsigned excl = incl - s;
    if (excl <= krem && krem < incl) { chs = t; runs = excl; }
    __syncthreads();
    int ch = chs;
    if (t < bpt) {
        unsigned g = 0;
        for (int j = 0; j < slots; ++j) g += hist[(ch * bpt + t) * slots + j];
        grp[t] = g;
    }
    __syncthreads();
    if (t == 0) {
        unsigned r2 = runs; int bsel = ch * bpt;
        for (int j = 0; j < bpt; ++j) {
            unsigned h = grp[j];
            if (r2 + h > krem) { bsel = ch * bpt + j; break; }
            r2 += h;
        }
        sel[0] = krem - r2;
        unsigned pref = (sel[1] << bits) | (unsigned)bsel;
        sel[1] = pref;
        if (final_stage) {
            unsigned fb = (pref & 0x80000000u) ? (pref ^ 0x80000000u) : ~pref;
            ((float*)sel)[2] = __uint_as_float(fb);
        }
    }
}

// ---------- K2: threshold + 7x7 maxpool + binarize*R ----------
__launch_bounds__(256, 7)
__global__ void harris_out(const float* __restrict__ R, const unsigned* __restrict__ sel,
                           float* __restrict__ out) {
    __shared__ float SR[38 * 72];   // rows y0-3..y0+34, cols x0-3..x0+66 (+2 junk)
    __shared__ float SM[38 * 64];   // horizontal thr-max, planar
    const float med = ((const float*)sel)[2];
    const int tid = threadIdx.x;
    const int tx = tid & 63, ty = tid >> 6;
    const int x0 = blockIdx.x * 64, y0 = blockIdx.y * 32, b = blockIdx.z;
    const float* Rb = R + (size_t)b * IMH * IMW;
    const bool interior = (x0 >= 3) && (x0 + 67 <= IMW) && (y0 >= 3) && (y0 + 35 <= IMH);

    if (interior) {
        const float* Rb0 = Rb + (size_t)(y0 - 3) * IMW + (x0 - 3);
        #pragma unroll
        for (int k = 0; k < 10; ++k) {
            int r = ty + 4 * k;
            if (r < 38) SR[r * 72 + tx] = Rb0[(size_t)r * IMW + tx];
        }
        if (tid < 228) {
            int r = tid / 6, c = 64 + (tid - r * 6);
            SR[r * 72 + c] = Rb0[(size_t)r * IMW + c];
        }
    } else {
        for (int i = tid; i < 38 * 70; i += 256) {
            int r = i / 70, c = i - r * 70;
            int gy = y0 - 3 + r, gx = x0 - 3 + c;
            float v = -INFINITY;
            if ((unsigned)gy < (unsigned)IMH && (unsigned)gx < (unsigned)IMW)
                v = Rb[(size_t)gy * IMW + gx];
            SR[r * 72 + c] = v;
        }
    }
    __syncthreads();

    #pragma unroll
    for (int k = 0; k < 10; ++k) {
        int r = ty + 4 * k;
        if (r < 38) {
            const float* p = SR + r * 72 + tx;
            float m = -INFINITY;
            #pragma unroll
            for (int d = 0; d < 7; ++d) {
                float v = p[d];
                float t = (v < med) ? ((v == -INFINITY) ? -INFINITY : 0.0f) : v;
                m = fmaxf(m, t);
            }
            SM[r * 64 + tx] = m;
        }
    }
    __syncthreads();

    // v-max: 8 consecutive rows per thread, shared max tree
    float vm[14];
    #pragma unroll
    for (int t = 0; t < 14; ++t) vm[t] = SM[(8 * ty + t) * 64 + tx];
    float m2[13], m4[11];
    #pragma unroll
    for (int i = 0; i < 13; ++i) m2[i] = fmaxf(vm[i], vm[i + 1]);
    #pragma unroll
    for (int i = 0; i < 11; ++i) m4[i] = fmaxf(m2[i], m2[i + 2]);
    float* ob = out + (size_t)b * IMH * IMW + (size_t)y0 * IMW + x0;
    #pragma unroll
    for (int j = 0; j < 8; ++j) {
        float pooled = fmaxf(m4[j], m4[j + 3]);
        float v = SR[(8 * ty + j + 3) * 72 + (tx + 3)];
        float t = (v < med) ? 0.0f : v;
        ob[(size_t)(8 * ty + j) * IMW + tx] = (t == pooled) ? v : 0.0f;
    }
}

extern "C" void kernel_launch(void* const* d_in, const int* in_sizes, int n_in,
                              void* d_out, int out_size, void* d_ws, size_t ws_size,
                              hipStream_t stream) {
    const float* x = (const float*)d_in[0];
    float* out = (float*)d_out;

    // ws: R (64MB) | h1[4096*8] | h2[4096] | h3[256] | sel[8]
    const size_t needed = (size_t)NPIX * 4 + (32768 + 4096 + 256 + 8) * 4;
    if (ws_size < needed) return;
    float* R = (float*)d_ws;
    unsigned* hbase = (unsigned*)((char*)d_ws + (size_t)NPIX * 4);
    unsigned* h1 = hbase;            // 32768 (4096 bins x 8 slots)
    unsigned* h2 = hbase + 32768;    // 4096
    unsigned* h3 = hbase + 36864;    // 256
    unsigned* sel = hbase + 37120;   // 8

    zero_kernel<<<(37128 + 255) / 256, 256, 0, stream>>>(hbase, 37128, 37120, KSEL);

    dim3 rgrid(IMW / 64, IMH / 16, NB);
    harris_R<<<rgrid, 256, 0, stream>>>(x, R, h1);

    select_kernel<<<1, 256, 0, stream>>>(h1, sel, 16, 12, 0, 8);
    hist2_kernel<<<2048, 256, 0, stream>>>(R, h2, sel);
    select_kernel<<<1, 256, 0, stream>>>(h2, sel, 16, 12, 0, 1);
    hist3_kernel<<<2048, 256, 0, stream>>>(R, h3, sel);
    select_kernel<<<1, 256, 0, stream>>>(h3, sel, 1, 8, 1, 1);

    dim3 ogrid(IMW / 64, IMH / 32, NB);
    harris_out<<<ogrid, 256, 0, stream>>>(R, sel, out);
}

// Round 5
// 320.159 us; speedup vs baseline: 1.4311x; 1.4311x over previous
//
#include <hip/hip_runtime.h>
#include <math.h>

constexpr int IMH = 2048, IMW = 2048, NB = 4;
constexpr int NPIX = NB * IMH * IMW;           // 16777216
constexpr unsigned KSEL = 8388607u;            // floor(0.5*(NPIX-1)) -> quantile 'lower'

__device__ __forceinline__ unsigned f2u(float f) {
    unsigned b = __float_as_uint(f);
    return (b & 0x80000000u) ? ~b : (b | 0x80000000u);
}

__device__ __forceinline__ void gauss7(float* a) {
    const double g0 = 0.8352702114112720;   // exp(-0.18)
    const double g1 = 0.9231163463866358;   // exp(-0.08)
    const double g2 = 0.9801986733067553;   // exp(-0.02)
    const double s = 2.0 * (g0 + g1 + g2) + 1.0;
    const double inv = 1.0 / s;
    a[0] = a[6] = (float)(g0 * inv);
    a[1] = a[5] = (float)(g1 * inv);
    a[2] = a[4] = (float)(g2 * inv);
    a[3] = (float)inv;
}

__device__ __forceinline__ float2 fmax2(float2 a, float2 b) {
    return make_float2(fmaxf(a.x, b.x), fmaxf(a.y, b.y));
}

// ---------- K1: Sobel + products + separable 7x7 Gaussian + R + hist1 ----------
// tile 64x32. LDS floats:
//   [0,7296)      STH2 f2[38*64] (sxx,syy) + STHx f[38*64] (sxy); SX 40x72 aliases start
//   [7296,12768)  SIXY4 f4[38*36] col-pairs (ix0,iy0,ix1,iy1); LH[4096] aliases
// NUMERICS CONTRACT: expression trees identical to round-2 (passed, absmax 1.0).
template<bool CHK>
__device__ __forceinline__ void sobel_stage(const float* SX, float4* SIXY4,
                                            int x0, int y0, int tid) {
    // 7 row-strips (6,6,6,6,6,6,2) x 70 cols; register row-window, r2 expression
    for (int i = tid; i < 490; i += 256) {
        int s = i / 70, c = i - s * 70;
        int r0 = 6 * s;
        int nr = (s == 6) ? 2 : 6;
        float xa[8], xm[8], xc[8];
        #pragma unroll
        for (int t = 0; t < 8; ++t) {
            if (t < nr + 2) {
                const float* row = SX + (r0 + t) * 72 + c;   // SX col c = image gx-1
                xa[t] = row[0]; xm[t] = row[1]; xc[t] = row[2];
            }
        }
        #pragma unroll
        for (int t = 0; t < 6; ++t) {
            if (t < nr) {
                int r = r0 + t;
                float x00 = xa[t],     x01 = xm[t],     x02 = xc[t];
                float x10 = xa[t + 1],                  x12 = xc[t + 1];
                float x20 = xa[t + 2], x21 = xm[t + 2], x22 = xc[t + 2];
                float ix = (x02 + 2.0f * x12 + x22) - (x00 + 2.0f * x10 + x20);
                float iy = (x20 + 2.0f * x21 + x22) - (x00 + 2.0f * x01 + x02);
                if (CHK) {
                    int gy = y0 - 3 + r, gx = x0 - 3 + c;
                    if (!((unsigned)gy < (unsigned)IMH && (unsigned)gx < (unsigned)IMW)) {
                        ix = 0.f; iy = 0.f;
                    }
                }
                ((float2*)(SIXY4 + r * 36 + (c >> 1)))[c & 1] = make_float2(ix, iy);
            }
        }
    }
}

__launch_bounds__(256, 3)
__global__ void harris_R(const float* __restrict__ x, float* __restrict__ Rout,
                         unsigned* __restrict__ hist) {
    __shared__ __align__(16) float smem[12768];   // 51072 B -> 3 blocks/CU
    float* SX = smem;                             // 40x72 (dead after sobel)
    float2* STH2 = (float2*)smem;                 // [38*64]
    float* STHx = smem + 4864;                    // [38*64]
    float4* SIXY4 = (float4*)(smem + 7296);       // [38*36]
    unsigned* LH = (unsigned*)(smem + 7296);      // 4096 bins (aliases SIXY4)

    const int tid = threadIdx.x;
    const int tx = tid & 63, ty = tid >> 6;
    const int x0 = blockIdx.x * 64, y0 = blockIdx.y * 32, b = blockIdx.z;
    const float* xb = x + (size_t)b * IMH * IMW;
    const bool interior = (x0 >= 4) && (x0 + 68 <= IMW) && (y0 >= 4) && (y0 + 36 <= IMH);

    // ---- stage x tile 40x72 (rows y0-4..y0+35, cols x0-4..x0+67), zero-padded ----
    if (interior) {
        const float* xp = xb + (size_t)(y0 - 4) * IMW + (x0 - 4);
        for (int i = tid; i < 1440; i += 256) {
            int r = i / 36, c2 = i - r * 36;
            *(float2*)&SX[r * 72 + 2 * c2] = *(const float2*)&xp[(size_t)r * IMW + 2 * c2];
        }
    } else {
        for (int i = tid; i < 2880; i += 256) {
            int r = i / 72, c = i - r * 72;
            int gy = y0 - 4 + r, gx = x0 - 4 + c;
            float v = 0.f;
            if ((unsigned)gy < (unsigned)IMH && (unsigned)gx < (unsigned)IMW)
                v = xb[(size_t)gy * IMW + gx];
            SX[r * 72 + c] = v;
        }
    }
    __syncthreads();

    if (interior) sobel_stage<false>(SX, SIXY4, x0, y0, tid);
    else          sobel_stage<true>(SX, SIXY4, x0, y0, tid);
    __syncthreads();   // SX dead; SIXY4 ready

    float a[7]; gauss7(a);

    // ---- h-blur + products: 38 rows x 32 col-pairs, r2 expression per column ----
    for (int i = tid; i < 38 * 32; i += 256) {
        int r = i >> 5, p = i & 31;
        const float4* base = SIXY4 + r * 36 + p;
        float4 q0 = base[0], q1 = base[1], q2 = base[2], q3 = base[3];
        float ix8[8] = {q0.x, q0.z, q1.x, q1.z, q2.x, q2.z, q3.x, q3.z};
        float iy8[8] = {q0.y, q0.w, q1.y, q1.w, q2.y, q2.w, q3.y, q3.w};
        float sxxA = 0.f, syyA = 0.f, sxyA = 0.f;
        float sxxB = 0.f, syyB = 0.f, sxyB = 0.f;
        #pragma unroll
        for (int d = 0; d < 7; ++d) {
            float tA = a[d] * ix8[d];
            sxxA += tA * ix8[d];
            sxyA += tA * iy8[d];
            syyA += (a[d] * iy8[d]) * iy8[d];
            float tB = a[d] * ix8[d + 1];
            sxxB += tB * ix8[d + 1];
            sxyB += tB * iy8[d + 1];
            syyB += (a[d] * iy8[d + 1]) * iy8[d + 1];
        }
        *(float4*)&STH2[r * 64 + 2 * p] = make_float4(sxxA, syyA, sxxB, syyB);
        *(float2*)&STHx[r * 64 + 2 * p] = make_float2(sxyA, sxyB);
    }
    __syncthreads();

    // ---- v-blur streaming (d ascending per output, r2 order) + R; hist zero ----
    for (int i = tid; i < 4096; i += 256) LH[i] = 0u;   // SIXY4 dead

    float axx[8] = {0, 0, 0, 0, 0, 0, 0, 0};
    float ayy[8] = {0, 0, 0, 0, 0, 0, 0, 0};
    float axy[8] = {0, 0, 0, 0, 0, 0, 0, 0};
    #pragma unroll
    for (int t = 0; t < 14; ++t) {
        float2 vv = STH2[(8 * ty + t) * 64 + tx];
        float vx = STHx[(8 * ty + t) * 64 + tx];
        #pragma unroll
        for (int j = 0; j < 8; ++j) {
            int d = t - j;
            if (d >= 0 && d < 7) {
                axx[j] += a[d] * vv.x;
                ayy[j] += a[d] * vv.y;
                axy[j] += a[d] * vx;
            }
        }
    }
    float rv[8];
    float* Rb = Rout + (size_t)b * IMH * IMW + (size_t)y0 * IMW + x0;
    #pragma unroll
    for (int j = 0; j < 8; ++j) {
        float sxx = axx[j], syy = ayy[j], sxy = axy[j];
        float tr = sxx + syy;
        float R = sxx * syy - sxy * sxy - 0.05f * tr * tr;
        rv[j] = R;
        Rb[(size_t)(8 * ty + j) * IMW + tx] = R;
    }
    __syncthreads();   // LH zeroing complete

    #pragma unroll
    for (int j = 0; j < 8; ++j) atomicAdd(&LH[f2u(rv[j]) >> 20], 1u);
    __syncthreads();

    const unsigned slot = ((blockIdx.z * gridDim.y + blockIdx.y) * gridDim.x + blockIdx.x) & 7u;
    for (int i = tid; i < 4096; i += 256) {
        unsigned c = LH[i];
        if (c) atomicAdd(&hist[i * 8 + slot], c);
    }
}

// ---------- median: radix select; pass 1 fused above (8-slot striped) ----------
__global__ void zero_kernel(unsigned* __restrict__ p, int n, int kidx, unsigned kval) {
    int i = blockIdx.x * blockDim.x + threadIdx.x;
    if (i < n) p[i] = (i == kidx) ? kval : 0u;
}

__global__ void hist2_kernel(const float* __restrict__ R, unsigned* __restrict__ hist,
                             const unsigned* __restrict__ sel) {
    __shared__ unsigned lh[4096];
    for (int i = threadIdx.x; i < 4096; i += 256) lh[i] = 0u;
    __syncthreads();
    const unsigned pref = sel[1];
    const float4* R4 = (const float4*)R;
    const int n4 = NPIX / 4;
    for (int i = blockIdx.x * 256 + threadIdx.x; i < n4; i += gridDim.x * 256) {
        float4 v = R4[i];
        unsigned u;
        u = f2u(v.x); if ((u >> 20) == pref) atomicAdd(&lh[(u >> 8) & 0xFFFu], 1u);
        u = f2u(v.y); if ((u >> 20) == pref) atomicAdd(&lh[(u >> 8) & 0xFFFu], 1u);
        u = f2u(v.z); if ((u >> 20) == pref) atomicAdd(&lh[(u >> 8) & 0xFFFu], 1u);
        u = f2u(v.w); if ((u >> 20) == pref) atomicAdd(&lh[(u >> 8) & 0xFFFu], 1u);
    }
    __syncthreads();
    for (int i = threadIdx.x; i < 4096; i += 256) { unsigned c = lh[i]; if (c) atomicAdd(&hist[i], c); }
}

__global__ void hist3_kernel(const float* __restrict__ R, unsigned* __restrict__ hist,
                             const unsigned* __restrict__ sel) {
    __shared__ unsigned lh[256];
    if (threadIdx.x < 256) lh[threadIdx.x] = 0u;
    __syncthreads();
    const unsigned pref = sel[1];
    const float4* R4 = (const float4*)R;
    const int n4 = NPIX / 4;
    for (int i = blockIdx.x * 256 + threadIdx.x; i < n4; i += gridDim.x * 256) {
        float4 v = R4[i];
        unsigned u;
        u = f2u(v.x); if ((u >> 8) == pref) atomicAdd(&lh[u & 0xFFu], 1u);
        u = f2u(v.y); if ((u >> 8) == pref) atomicAdd(&lh[u & 0xFFu], 1u);
        u = f2u(v.z); if ((u >> 8) == pref) atomicAdd(&lh[u & 0xFFu], 1u);
        u = f2u(v.w); if ((u >> 8) == pref) atomicAdd(&lh[u & 0xFFu], 1u);
    }
    __syncthreads();
    { unsigned c = lh[threadIdx.x]; if (c) atomicAdd(&hist[threadIdx.x], c); }
}

__global__ void select_kernel(const unsigned* __restrict__ hist, unsigned* __restrict__ sel,
                              int bpt, int bits, int final_stage, int slots) {
    __shared__ unsigned part[256];
    __shared__ unsigned grp[16];
    __shared__ int chs;
    __shared__ unsigned runs;
    const int t = threadIdx.x;
    const unsigned krem = sel[0];
    unsigned s = 0;
    for (int i = 0; i < bpt; ++i) {
        unsigned bsum = 0;
        for (int j = 0; j < slots; ++j) bsum += hist[(t * bpt + i) * slots + j];
        s += bsum;
    }
    part[t] = s;
    __syncthreads();
    #pragma unroll
    for (int off = 1; off < 256; off <<= 1) {
        unsigned add = (t >= off) ? part[t - off] : 0u;
        __syncthreads();
        part[t] += add;
        __syncthreads();
    }
    unsigned incl = part[t];
    unsigned excl = incl - s;
    if (excl <= krem && krem < incl) { chs = t; runs = excl; }
    __syncthreads();
    int ch = chs;
    if (t < bpt) {
        unsigned g = 0;
        for (int j = 0; j < slots; ++j) g += hist[(ch * bpt + t) * slots + j];
        grp[t] = g;
    }
    __syncthreads();
    if (t == 0) {
        unsigned r2 = runs; int bsel = ch * bpt;
        for (int j = 0; j < bpt; ++j) {
            unsigned h = grp[j];
            if (r2 + h > krem) { bsel = ch * bpt + j; break; }
            r2 += h;
        }
        sel[0] = krem - r2;
        unsigned pref = (sel[1] << bits) | (unsigned)bsel;
        sel[1] = pref;
        if (final_stage) {
            unsigned fb = (pref & 0x80000000u) ? (pref ^ 0x80000000u) : ~pref;
            ((float*)sel)[2] = __uint_as_float(fb);
        }
    }
}

// ---------- K2: threshold + 7x7 maxpool + binarize*R, tile 64x64 ----------
__launch_bounds__(256, 4)
__global__ void harris_out(const float* __restrict__ R, const unsigned* __restrict__ sel,
                           float* __restrict__ out) {
    __shared__ __align__(16) float smem2[9520];   // 38080 B -> 4 blocks/CU
    float* SR = smem2;                            // [70*72] raw R halo 3, OOB=-inf
    float2* SM2 = (float2*)(smem2 + 5040);        // [70*32] horizontal thr-max col pairs
    const float med = ((const float*)sel)[2];
    const int tid = threadIdx.x;
    const int x0 = blockIdx.x * 64, y0 = blockIdx.y * 64, b = blockIdx.z;
    const float* Rb = R + (size_t)b * IMH * IMW;

    for (int i = tid; i < 70 * 70; i += 256) {
        int r = i / 70, c = i - r * 70;
        int gy = y0 - 3 + r, gx = x0 - 3 + c;
        float v = -INFINITY;
        if ((unsigned)gy < (unsigned)IMH && (unsigned)gx < (unsigned)IMW)
            v = Rb[(size_t)gy * IMW + gx];
        SR[r * 72 + c] = v;
    }
    __syncthreads();

    // h-max over thresholded values: 70 rows x 32 pairs (max reassoc is exact)
    for (int i = tid; i < 70 * 32; i += 256) {
        int r = i >> 5, p = i & 31;
        const float2* u = (const float2*)(SR + r * 72 + 2 * p);
        float2 u0 = u[0], u1 = u[1], u2 = u[2], u3 = u[3];
        float cv[8] = {u0.x, u0.y, u1.x, u1.y, u2.x, u2.y, u3.x, u3.y};
        float tv[8];
        #pragma unroll
        for (int k = 0; k < 8; ++k) {
            float v = cv[k];
            tv[k] = (v < med) ? ((v == -INFINITY) ? -INFINITY : 0.0f) : v;
        }
        float mid = fmaxf(fmaxf(fmaxf(tv[1], tv[2]), fmaxf(tv[3], tv[4])), fmaxf(tv[5], tv[6]));
        SM2[r * 32 + p] = make_float2(fmaxf(tv[0], mid), fmaxf(tv[7], mid));
    }
    __syncthreads();

    // v-max (f2 tree) + binarize
    const int p = tid & 31, g = tid >> 5;
    float2 vm[14];
    #pragma unroll
    for (int t = 0; t < 14; ++t) vm[t] = SM2[(8 * g + t) * 32 + p];
    float2 m2[13];
    #pragma unroll
    for (int i = 0; i < 13; ++i) m2[i] = fmax2(vm[i], vm[i + 1]);
    float2 m4[11];
    #pragma unroll
    for (int i = 0; i < 11; ++i) m4[i] = fmax2(m2[i], m2[i + 2]);
    float* ob = out + (size_t)b * IMH * IMW + (size_t)y0 * IMW + x0;
    #pragma unroll
    for (int j = 0; j < 8; ++j) {
        float2 pooled = fmax2(m4[j], m4[j + 3]);
        float vA = SR[(8 * g + j + 3) * 72 + 2 * p + 3];
        float vB = SR[(8 * g + j + 3) * 72 + 2 * p + 4];
        float tA = (vA < med) ? 0.0f : vA;
        float tB = (vB < med) ? 0.0f : vB;
        float2 o = make_float2((tA == pooled.x) ? vA : 0.0f, (tB == pooled.y) ? vB : 0.0f);
        *(float2*)&ob[(size_t)(8 * g + j) * IMW + 2 * p] = o;
    }
}

extern "C" void kernel_launch(void* const* d_in, const int* in_sizes, int n_in,
                              void* d_out, int out_size, void* d_ws, size_t ws_size,
                              hipStream_t stream) {
    const float* x = (const float*)d_in[0];
    float* out = (float*)d_out;

    // ws: R (64MB) | h1[4096*8] | h2[4096] | h3[256] | sel[8]
    const size_t needed = (size_t)NPIX * 4 + (32768 + 4096 + 256 + 8) * 4;
    if (ws_size < needed) return;
    float* R = (float*)d_ws;
    unsigned* hbase = (unsigned*)((char*)d_ws + (size_t)NPIX * 4);
    unsigned* h1 = hbase;            // 32768 (4096 bins x 8 slots)
    unsigned* h2 = hbase + 32768;    // 4096
    unsigned* h3 = hbase + 36864;    // 256
    unsigned* sel = hbase + 37120;   // 8

    zero_kernel<<<(37128 + 255) / 256, 256, 0, stream>>>(hbase, 37128, 37120, KSEL);

    dim3 rgrid(IMW / 64, IMH / 32, NB);
    harris_R<<<rgrid, 256, 0, stream>>>(x, R, h1);

    select_kernel<<<1, 256, 0, stream>>>(h1, sel, 16, 12, 0, 8);
    hist2_kernel<<<2048, 256, 0, stream>>>(R, h2, sel);
    select_kernel<<<1, 256, 0, stream>>>(h2, sel, 16, 12, 0, 1);
    hist3_kernel<<<2048, 256, 0, stream>>>(R, h3, sel);
    select_kernel<<<1, 256, 0, stream>>>(h3, sel, 1, 8, 1, 1);

    dim3 ogrid(IMW / 64, IMH / 64, NB);
    harris_out<<<ogrid, 256, 0, stream>>>(R, sel, out);
}

// Round 6
// 302.005 us; speedup vs baseline: 1.5171x; 1.0601x over previous
//
#include <hip/hip_runtime.h>
#include <math.h>

constexpr int IMH = 2048, IMW = 2048, NB = 4;
constexpr int NPIX = NB * IMH * IMW;           // 16777216
constexpr unsigned KSEL = 8388607u;            // floor(0.5*(NPIX-1)) -> quantile 'lower'

__device__ __forceinline__ unsigned f2u(float f) {
    unsigned b = __float_as_uint(f);
    return (b & 0x80000000u) ? ~b : (b | 0x80000000u);
}

__device__ __forceinline__ void gauss7(float* a) {
    const double g0 = 0.8352702114112720;   // exp(-0.18)
    const double g1 = 0.9231163463866358;   // exp(-0.08)
    const double g2 = 0.9801986733067553;   // exp(-0.02)
    const double s = 2.0 * (g0 + g1 + g2) + 1.0;
    const double inv = 1.0 / s;
    a[0] = a[6] = (float)(g0 * inv);
    a[1] = a[5] = (float)(g1 * inv);
    a[2] = a[4] = (float)(g2 * inv);
    a[3] = (float)inv;
}

__device__ __forceinline__ float2 fmax2(float2 a, float2 b) {
    return make_float2(fmaxf(a.x, b.x), fmaxf(a.y, b.y));
}

// ---------- K1: Sobel + products + separable 7x7 Gaussian + R + hist1 ----------
// tile 64x32, 512 threads. LDS floats (total 12768 f = 51072 B -> 3 blocks/CU, 24 waves):
//   SIXY f2[38][72] @ [0,5472)        (cols 0..69 valid); LH[4096] aliases after h-blur
//   SX   f [40][72] @ [5472,8352)     (dead after sobel)
//   STH  3 planes f[38][64] @ [5472, 12768)  (plane p at 5472 + p*2432; overlays dead SX)
// NUMERICS CONTRACT: expression trees identical to rounds 2/5 (passed, absmax 1.0).
__launch_bounds__(512, 6)
__global__ void harris_R(const float* __restrict__ x, float* __restrict__ Rout,
                         unsigned* __restrict__ hist) {
    __shared__ __align__(16) float smem[12768];
    float2* SIXY = (float2*)smem;            // [38][72] f2
    float* SX = smem + 5472;                 // [40][72]
    float* STH = smem + 5472;                // 3 x [38][64]
    unsigned* LH = (unsigned*)smem;          // [4096]

    const int tid = threadIdx.x;
    const int tx = tid & 63, ty = tid >> 6;  // ty in 0..7
    const int x0 = blockIdx.x * 64, y0 = blockIdx.y * 32, b = blockIdx.z;
    const float* xb = x + (size_t)b * IMH * IMW;
    const bool interior = (x0 >= 4) && (x0 + 68 <= IMW) && (y0 >= 4) && (y0 + 36 <= IMH);

    // ---- stage x tile 40x72 (rows y0-4..y0+35, cols x0-4..x0+67), zero-padded ----
    if (interior) {
        const float* xp = xb + (size_t)(y0 - 4) * IMW + (x0 - 4);
        for (int i = tid; i < 1440; i += 512) {
            int r = i / 36, c2 = i - r * 36;
            *(float2*)&SX[r * 72 + 2 * c2] = *(const float2*)&xp[(size_t)r * IMW + 2 * c2];
        }
    } else {
        for (int i = tid; i < 2880; i += 512) {
            int r = i / 72, c = i - r * 72;
            int gy = y0 - 4 + r, gx = x0 - 4 + c;
            float v = 0.f;
            if ((unsigned)gy < (unsigned)IMH && (unsigned)gx < (unsigned)IMW)
                v = xb[(size_t)gy * IMW + gx];
            SX[r * 72 + c] = v;
        }
    }
    __syncthreads();

    // ---- Sobel 38x70 -> SIXY (zero outside image); r2 expression ----
    for (int i = tid; i < 2660; i += 512) {
        int r = i / 70, c = i - r * 70;
        const float* p = SX + r * 72 + c;    // x[gy-1][gx-1]
        float x00 = p[0], x01 = p[1], x02 = p[2];
        float x10 = p[72], x12 = p[74];
        float x20 = p[144], x21 = p[145], x22 = p[146];
        float ix = (x02 + 2.0f * x12 + x22) - (x00 + 2.0f * x10 + x20);
        float iy = (x20 + 2.0f * x21 + x22) - (x00 + 2.0f * x01 + x02);
        if (!interior) {
            int gy = y0 - 3 + r, gx = x0 - 3 + c;
            if (!((unsigned)gy < (unsigned)IMH && (unsigned)gx < (unsigned)IMW)) {
                ix = 0.f; iy = 0.f;
            }
        }
        SIXY[r * 72 + c] = make_float2(ix, iy);
    }
    __syncthreads();

    float a[7]; gauss7(a);

    // ---- h-blur + products: 38 rows x 64 cols -> 3 planar STH (overlays dead SX) ----
    for (int i = tid; i < 2432; i += 512) {
        int r = i >> 6, c = i & 63;
        const float2* p = SIXY + r * 72 + c;
        float sxx = 0.f, syy = 0.f, sxy = 0.f;
        #pragma unroll
        for (int d = 0; d < 7; ++d) {
            float2 v = p[d];
            float t = a[d] * v.x;
            sxx += t * v.x;
            sxy += t * v.y;
            syy += (a[d] * v.y) * v.y;
        }
        STH[r * 64 + c] = sxx;
        STH[2432 + r * 64 + c] = syy;
        STH[4864 + r * 64 + c] = sxy;
    }
    __syncthreads();

    // ---- hist zero (dead SIXY) + v-blur streaming window, 4 consecutive rows/thread ----
    for (int i = tid; i < 4096; i += 512) LH[i] = 0u;

    float vxx[10], vyy[10], vxy[10];
    {
        const float* base = STH + (4 * ty) * 64 + tx;
        #pragma unroll
        for (int t = 0; t < 10; ++t) {
            vxx[t] = base[t * 64];
            vyy[t] = base[2432 + t * 64];
            vxy[t] = base[4864 + t * 64];
        }
    }
    float rv[4];
    float* Rb = Rout + (size_t)b * IMH * IMW + (size_t)y0 * IMW + x0;
    #pragma unroll
    for (int j = 0; j < 4; ++j) {
        float sxx = 0.f, syy = 0.f, sxy = 0.f;
        #pragma unroll
        for (int d = 0; d < 7; ++d) {
            sxx += a[d] * vxx[j + d];
            syy += a[d] * vyy[j + d];
            sxy += a[d] * vxy[j + d];
        }
        float tr = sxx + syy;
        float R = sxx * syy - sxy * sxy - 0.05f * tr * tr;
        rv[j] = R;
        Rb[(size_t)(4 * ty + j) * IMW + tx] = R;
    }
    __syncthreads();   // LH zeroing complete

    #pragma unroll
    for (int j = 0; j < 4; ++j) atomicAdd(&LH[f2u(rv[j]) >> 20], 1u);
    __syncthreads();

    const unsigned slot = ((blockIdx.z * gridDim.y + blockIdx.y) * gridDim.x + blockIdx.x) & 7u;
    for (int i = tid; i < 4096; i += 512) {
        unsigned c = LH[i];
        if (c) atomicAdd(&hist[i * 8 + slot], c);
    }
}

// ---------- median: radix select; pass 1 fused above (8-slot striped) ----------
__global__ void zero_kernel(unsigned* __restrict__ p, int n, int kidx, unsigned kval) {
    int i = blockIdx.x * blockDim.x + threadIdx.x;
    if (i < n) p[i] = (i == kidx) ? kval : 0u;
}

__global__ void hist2_kernel(const float* __restrict__ R, unsigned* __restrict__ hist,
                             const unsigned* __restrict__ sel) {
    __shared__ unsigned lh[4096];
    for (int i = threadIdx.x; i < 4096; i += 256) lh[i] = 0u;
    __syncthreads();
    const unsigned pref = sel[1];
    const float4* R4 = (const float4*)R;
    const int n4 = NPIX / 4;
    for (int i = blockIdx.x * 256 + threadIdx.x; i < n4; i += gridDim.x * 256) {
        float4 v = R4[i];
        unsigned u;
        u = f2u(v.x); if ((u >> 20) == pref) atomicAdd(&lh[(u >> 8) & 0xFFFu], 1u);
        u = f2u(v.y); if ((u >> 20) == pref) atomicAdd(&lh[(u >> 8) & 0xFFFu], 1u);
        u = f2u(v.z); if ((u >> 20) == pref) atomicAdd(&lh[(u >> 8) & 0xFFFu], 1u);
        u = f2u(v.w); if ((u >> 20) == pref) atomicAdd(&lh[(u >> 8) & 0xFFFu], 1u);
    }
    __syncthreads();
    for (int i = threadIdx.x; i < 4096; i += 256) { unsigned c = lh[i]; if (c) atomicAdd(&hist[i], c); }
}

__global__ void hist3_kernel(const float* __restrict__ R, unsigned* __restrict__ hist,
                             const unsigned* __restrict__ sel) {
    __shared__ unsigned lh[256];
    if (threadIdx.x < 256) lh[threadIdx.x] = 0u;
    __syncthreads();
    const unsigned pref = sel[1];
    const float4* R4 = (const float4*)R;
    const int n4 = NPIX / 4;
    for (int i = blockIdx.x * 256 + threadIdx.x; i < n4; i += gridDim.x * 256) {
        float4 v = R4[i];
        unsigned u;
        u = f2u(v.x); if ((u >> 8) == pref) atomicAdd(&lh[u & 0xFFu], 1u);
        u = f2u(v.y); if ((u >> 8) == pref) atomicAdd(&lh[u & 0xFFu], 1u);
        u = f2u(v.z); if ((u >> 8) == pref) atomicAdd(&lh[u & 0xFFu], 1u);
        u = f2u(v.w); if ((u >> 8) == pref) atomicAdd(&lh[u & 0xFFu], 1u);
    }
    __syncthreads();
    { unsigned c = lh[threadIdx.x]; if (c) atomicAdd(&hist[threadIdx.x], c); }
}

__global__ void select_kernel(const unsigned* __restrict__ hist, unsigned* __restrict__ sel,
                              int bpt, int bits, int final_stage, int slots) {
    __shared__ unsigned part[256];
    __shared__ unsigned grp[16];
    __shared__ int chs;
    __shared__ unsigned runs;
    const int t = threadIdx.x;
    const unsigned krem = sel[0];
    unsigned s = 0;
    for (int i = 0; i < bpt; ++i) {
        unsigned bsum = 0;
        for (int j = 0; j < slots; ++j) bsum += hist[(t * bpt + i) * slots + j];
        s += bsum;
    }
    part[t] = s;
    __syncthreads();
    #pragma unroll
    for (int off = 1; off < 256; off <<= 1) {
        unsigned add = (t >= off) ? part[t - off] : 0u;
        __syncthreads();
        part[t] += add;
        __syncthreads();
    }
    unsigned incl = part[t];
    unsigned excl = incl - s;
    if (excl <= krem && krem < incl) { chs = t; runs = excl; }
    __syncthreads();
    int ch = chs;
    if (t < bpt) {
        unsigned g = 0;
        for (int j = 0; j < slots; ++j) g += hist[(ch * bpt + t) * slots + j];
        grp[t] = g;
    }
    __syncthreads();
    if (t == 0) {
        unsigned r2 = runs; int bsel = ch * bpt;
        for (int j = 0; j < bpt; ++j) {
            unsigned h = grp[j];
            if (r2 + h > krem) { bsel = ch * bpt + j; break; }
            r2 += h;
        }
        sel[0] = krem - r2;
        unsigned pref = (sel[1] << bits) | (unsigned)bsel;
        sel[1] = pref;
        if (final_stage) {
            unsigned fb = (pref & 0x80000000u) ? (pref ^ 0x80000000u) : ~pref;
            ((float*)sel)[2] = __uint_as_float(fb);
        }
    }
}

// ---------- K2: threshold + 7x7 maxpool + binarize*R, tile 64x64, 512 threads ----------
__launch_bounds__(512, 6)
__global__ void harris_out(const float* __restrict__ R, const unsigned* __restrict__ sel,
                           float* __restrict__ out) {
    __shared__ __align__(16) float smem2[9520];   // 38080 B
    float* SR = smem2;                            // [70*72] raw R halo 3, OOB=-inf
    float2* SM2 = (float2*)(smem2 + 5040);        // [70*32] horizontal thr-max col pairs
    const float med = ((const float*)sel)[2];
    const int tid = threadIdx.x;
    const int x0 = blockIdx.x * 64, y0 = blockIdx.y * 64, b = blockIdx.z;
    const float* Rb = R + (size_t)b * IMH * IMW;

    for (int i = tid; i < 70 * 70; i += 512) {
        int r = i / 70, c = i - r * 70;
        int gy = y0 - 3 + r, gx = x0 - 3 + c;
        float v = -INFINITY;
        if ((unsigned)gy < (unsigned)IMH && (unsigned)gx < (unsigned)IMW)
            v = Rb[(size_t)gy * IMW + gx];
        SR[r * 72 + c] = v;
    }
    __syncthreads();

    // h-max over thresholded values: 70 rows x 32 pairs (max reassoc is exact)
    for (int i = tid; i < 70 * 32; i += 512) {
        int r = i >> 5, p = i & 31;
        const float2* u = (const float2*)(SR + r * 72 + 2 * p);
        float2 u0 = u[0], u1 = u[1], u2 = u[2], u3 = u[3];
        float cv[8] = {u0.x, u0.y, u1.x, u1.y, u2.x, u2.y, u3.x, u3.y};
        float tv[8];
        #pragma unroll
        for (int k = 0; k < 8; ++k) {
            float v = cv[k];
            tv[k] = (v < med) ? ((v == -INFINITY) ? -INFINITY : 0.0f) : v;
        }
        float mid = fmaxf(fmaxf(fmaxf(tv[1], tv[2]), fmaxf(tv[3], tv[4])), fmaxf(tv[5], tv[6]));
        SM2[r * 32 + p] = make_float2(fmaxf(tv[0], mid), fmaxf(tv[7], mid));
    }
    __syncthreads();

    // v-max (f2 tree) + binarize: thread = (pair p, rowgroup g of 4 rows)
    const int p = tid & 31, g = tid >> 5;     // g in 0..15
    float2 vm[10];
    #pragma unroll
    for (int t = 0; t < 10; ++t) vm[t] = SM2[(4 * g + t) * 32 + p];
    float2 m2[9];
    #pragma unroll
    for (int i = 0; i < 9; ++i) m2[i] = fmax2(vm[i], vm[i + 1]);
    float2 m4[7];
    #pragma unroll
    for (int i = 0; i < 7; ++i) m4[i] = fmax2(m2[i], m2[i + 2]);
    float* ob = out + (size_t)b * IMH * IMW + (size_t)y0 * IMW + x0;
    #pragma unroll
    for (int j = 0; j < 4; ++j) {
        float2 pooled = fmax2(m4[j], m4[j + 3]);
        float vA = SR[(4 * g + j + 3) * 72 + 2 * p + 3];
        float vB = SR[(4 * g + j + 3) * 72 + 2 * p + 4];
        float tA = (vA < med) ? 0.0f : vA;
        float tB = (vB < med) ? 0.0f : vB;
        float2 o = make_float2((tA == pooled.x) ? vA : 0.0f, (tB == pooled.y) ? vB : 0.0f);
        *(float2*)&ob[(size_t)(4 * g + j) * IMW + 2 * p] = o;
    }
}

extern "C" void kernel_launch(void* const* d_in, const int* in_sizes, int n_in,
                              void* d_out, int out_size, void* d_ws, size_t ws_size,
                              hipStream_t stream) {
    const float* x = (const float*)d_in[0];
    float* out = (float*)d_out;

    // ws: R (64MB) | h1[4096*8] | h2[4096] | h3[256] | sel[8]
    const size_t needed = (size_t)NPIX * 4 + (32768 + 4096 + 256 + 8) * 4;
    if (ws_size < needed) return;
    float* R = (float*)d_ws;
    unsigned* hbase = (unsigned*)((char*)d_ws + (size_t)NPIX * 4);
    unsigned* h1 = hbase;            // 32768 (4096 bins x 8 slots)
    unsigned* h2 = hbase + 32768;    // 4096
    unsigned* h3 = hbase + 36864;    // 256
    unsigned* sel = hbase + 37120;   // 8

    zero_kernel<<<(37128 + 255) / 256, 256, 0, stream>>>(hbase, 37128, 37120, KSEL);

    dim3 rgrid(IMW / 64, IMH / 32, NB);
    harris_R<<<rgrid, 512, 0, stream>>>(x, R, h1);

    select_kernel<<<1, 256, 0, stream>>>(h1, sel, 16, 12, 0, 8);
    hist2_kernel<<<2048, 256, 0, stream>>>(R, h2, sel);
    select_kernel<<<1, 256, 0, stream>>>(h2, sel, 16, 12, 0, 1);
    hist3_kernel<<<2048, 256, 0, stream>>>(R, h3, sel);
    select_kernel<<<1, 256, 0, stream>>>(h3, sel, 1, 8, 1, 1);

    dim3 ogrid(IMW / 64, IMH / 64, NB);
    harris_out<<<ogrid, 512, 0, stream>>>(R, sel, out);
}

// Round 7
// 300.275 us; speedup vs baseline: 1.5259x; 1.0058x over previous
//
#include <hip/hip_runtime.h>
#include <math.h>

constexpr int IMH = 2048, IMW = 2048, NB = 4;
constexpr int NPIX = NB * IMH * IMW;           // 16777216
constexpr unsigned KSEL = 8388607u;            // floor(0.5*(NPIX-1)) -> quantile 'lower'

__device__ __forceinline__ unsigned f2u(float f) {
    unsigned b = __float_as_uint(f);
    return (b & 0x80000000u) ? ~b : (b | 0x80000000u);
}

__device__ __forceinline__ void gauss7(float* a) {
    const double g0 = 0.8352702114112720;   // exp(-0.18)
    const double g1 = 0.9231163463866358;   // exp(-0.08)
    const double g2 = 0.9801986733067553;   // exp(-0.02)
    const double s = 2.0 * (g0 + g1 + g2) + 1.0;
    const double inv = 1.0 / s;
    a[0] = a[6] = (float)(g0 * inv);
    a[1] = a[5] = (float)(g1 * inv);
    a[2] = a[4] = (float)(g2 * inv);
    a[3] = (float)inv;
}

__device__ __forceinline__ float2 fmax2(float2 a, float2 b) {
    return make_float2(fmaxf(a.x, b.x), fmaxf(a.y, b.y));
}

// Sobel for NW consecutive columns starting at SIXY col sb (r2 expression tree).
template<int NW>
__device__ __forceinline__ void sobel_group(const float* SX, float2* SIXY, int r, int sb) {
    float w0[6], w1[6], w2[6];
    const float* p0 = SX + r * 72 + sb;
    const float* p1 = p0 + 72;
    const float* p2 = p1 + 72;
    float4 A0 = *(const float4*)p0;
    float4 A1 = *(const float4*)p1;
    float4 A2 = *(const float4*)p2;
    w0[0] = A0.x; w0[1] = A0.y; w0[2] = A0.z; w0[3] = A0.w;
    w1[0] = A1.x; w1[1] = A1.y; w1[2] = A1.z; w1[3] = A1.w;
    w2[0] = A2.x; w2[1] = A2.y; w2[2] = A2.z; w2[3] = A2.w;
    if (NW == 4) {
        float2 B0 = *(const float2*)(p0 + 4);
        float2 B1 = *(const float2*)(p1 + 4);
        float2 B2 = *(const float2*)(p2 + 4);
        w0[4] = B0.x; w0[5] = B0.y;
        w1[4] = B1.x; w1[5] = B1.y;
        w2[4] = B2.x; w2[5] = B2.y;
    }
    float2 ov[NW];
    #pragma unroll
    for (int j = 0; j < NW; ++j) {
        float x00 = w0[j], x01 = w0[j + 1], x02 = w0[j + 2];
        float x10 = w1[j],                  x12 = w1[j + 2];
        float x20 = w2[j], x21 = w2[j + 1], x22 = w2[j + 2];
        float ix = (x02 + 2.0f * x12 + x22) - (x00 + 2.0f * x10 + x20);
        float iy = (x20 + 2.0f * x21 + x22) - (x00 + 2.0f * x01 + x02);
        ov[j] = make_float2(ix, iy);
    }
    *(float4*)&SIXY[r * 72 + sb] = make_float4(ov[0].x, ov[0].y, ov[1].x, ov[1].y);
    if (NW == 4)
        *(float4*)&SIXY[r * 72 + sb + 2] = make_float4(ov[2].x, ov[2].y, ov[3].x, ov[3].y);
}

// h-blur + products for 4 cols (r2 expression tree, d ascending), planar STH writes.
__device__ __forceinline__ void hblur_group(const float2* SIXY, float* STH,
                                            const float* a, int r, int g) {
    const float2* base = SIXY + r * 72 + 4 * g;
    float4 A = *(const float4*)(base + 0);
    float4 B = *(const float4*)(base + 2);
    float4 C = *(const float4*)(base + 4);
    float4 D = *(const float4*)(base + 6);
    float4 E = *(const float4*)(base + 8);
    float2 q[10];
    q[0] = make_float2(A.x, A.y); q[1] = make_float2(A.z, A.w);
    q[2] = make_float2(B.x, B.y); q[3] = make_float2(B.z, B.w);
    q[4] = make_float2(C.x, C.y); q[5] = make_float2(C.z, C.w);
    q[6] = make_float2(D.x, D.y); q[7] = make_float2(D.z, D.w);
    q[8] = make_float2(E.x, E.y); q[9] = make_float2(E.z, E.w);
    float sxx[4], syy[4], sxy[4];
    #pragma unroll
    for (int j = 0; j < 4; ++j) {
        float xx = 0.f, yy = 0.f, xy = 0.f;
        #pragma unroll
        for (int d = 0; d < 7; ++d) {
            float2 v = q[j + d];
            float t = a[d] * v.x;
            xx += t * v.x;
            xy += t * v.y;
            yy += (a[d] * v.y) * v.y;
        }
        sxx[j] = xx; syy[j] = yy; sxy[j] = xy;
    }
    *(float4*)&STH[r * 64 + 4 * g]        = make_float4(sxx[0], sxx[1], sxx[2], sxx[3]);
    *(float4*)&STH[2432 + r * 64 + 4 * g] = make_float4(syy[0], syy[1], syy[2], syy[3]);
    *(float4*)&STH[4864 + r * 64 + 4 * g] = make_float4(sxy[0], sxy[1], sxy[2], sxy[3]);
}

// ---------- K1: Sobel + products + separable 7x7 Gaussian + R + hist1 ----------
// tile 64x32, 512 threads. LDS floats (12768 f = 51072 B -> 3 blocks/CU):
//   SIXY f2[38][72] @ [0,5472)      ; LH[4096] aliases after h-blur
//   SX   f [40][72] @ [5472,8352)   (dead after sobel)
//   STH  3 planes f[38][64] @ [5472,12768) (overlays dead SX)
// NUMERICS CONTRACT: expression trees identical to rounds 2/5/6 (passed, absmax 1.0).
__launch_bounds__(512, 6)
__global__ void harris_R(const float* __restrict__ x, float* __restrict__ Rout,
                         unsigned* __restrict__ hist) {
    __shared__ __align__(16) float smem[12768];
    float2* SIXY = (float2*)smem;            // [38][72] f2
    float* SX = smem + 5472;                 // [40][72]
    float* STH = smem + 5472;                // 3 x [38][64]
    unsigned* LH = (unsigned*)smem;          // [4096]

    const int tid = threadIdx.x;
    const int tx = tid & 63, ty = tid >> 6;  // for vblur phase
    const int x0 = blockIdx.x * 64, y0 = blockIdx.y * 32, b = blockIdx.z;
    const float* xb = x + (size_t)b * IMH * IMW;
    const bool interior = (x0 >= 4) && (x0 + 68 <= IMW) && (y0 >= 4) && (y0 + 36 <= IMH);

    // ---- stage x tile 40x72 (rows y0-4..y0+35, cols x0-4..x0+67), zero-padded ----
    if (interior) {
        const float* xp = xb + (size_t)(y0 - 4) * IMW + (x0 - 4);
        int r = tid >> 4, k = tid & 15;
        *(float4*)&SX[r * 72 + 4 * k] = *(const float4*)&xp[(size_t)r * IMW + 4 * k];
        if (tid < 128) {
            int r2 = 32 + (tid >> 4);
            *(float4*)&SX[r2 * 72 + 4 * k] = *(const float4*)&xp[(size_t)r2 * IMW + 4 * k];
        }
        if (tid < 80) {
            int r3 = tid >> 1, k3 = 16 + (tid & 1);
            *(float4*)&SX[r3 * 72 + 4 * k3] = *(const float4*)&xp[(size_t)r3 * IMW + 4 * k3];
        }
    } else {
        for (int i = tid; i < 2880; i += 512) {
            int r = i / 72, c = i - r * 72;
            int gy = y0 - 4 + r, gx = x0 - 4 + c;
            float v = 0.f;
            if ((unsigned)gy < (unsigned)IMH && (unsigned)gx < (unsigned)IMW)
                v = xb[(size_t)gy * IMW + gx];
            SX[r * 72 + c] = v;
        }
    }
    __syncthreads();

    // ---- Sobel 38x70 -> SIXY ----
    if (interior) {
        {
            int r = tid >> 4, g = tid & 15;
            sobel_group<4>(SX, SIXY, r, 4 * g);
        }
        if (tid < 96) {
            int r = 32 + (tid >> 4), g = tid & 15;
            sobel_group<4>(SX, SIXY, r, 4 * g);
        }
        if (tid < 76) {
            int r = tid >> 1;
            if (tid & 1) sobel_group<2>(SX, SIXY, r, 68);
            else         sobel_group<4>(SX, SIXY, r, 64);
        }
    } else {
        for (int i = tid; i < 2660; i += 512) {
            int r = i / 70, c = i - r * 70;
            const float* p = SX + r * 72 + c;
            float x00 = p[0], x01 = p[1], x02 = p[2];
            float x10 = p[72], x12 = p[74];
            float x20 = p[144], x21 = p[145], x22 = p[146];
            float ix = (x02 + 2.0f * x12 + x22) - (x00 + 2.0f * x10 + x20);
            float iy = (x20 + 2.0f * x21 + x22) - (x00 + 2.0f * x01 + x02);
            int gy = y0 - 3 + r, gx = x0 - 3 + c;
            if (!((unsigned)gy < (unsigned)IMH && (unsigned)gx < (unsigned)IMW)) {
                ix = 0.f; iy = 0.f;
            }
            SIXY[r * 72 + c] = make_float2(ix, iy);
        }
    }
    __syncthreads();

    float a[7]; gauss7(a);

    // ---- h-blur + products: 38 rows x 16 col-groups -> 3 planar STH ----
    {
        int r = tid >> 4, g = tid & 15;
        hblur_group(SIXY, STH, a, r, g);
    }
    if (tid < 96) {
        int r = 32 + (tid >> 4), g = tid & 15;
        hblur_group(SIXY, STH, a, r, g);
    }
    __syncthreads();

    // ---- hist zero (dead SIXY) + v-blur streaming window, 4 consecutive rows/thread ----
    for (int i = tid; i < 4096; i += 512) LH[i] = 0u;

    float vxx[10], vyy[10], vxy[10];
    {
        const float* base = STH + (4 * ty) * 64 + tx;
        #pragma unroll
        for (int t = 0; t < 10; ++t) {
            vxx[t] = base[t * 64];
            vyy[t] = base[2432 + t * 64];
            vxy[t] = base[4864 + t * 64];
        }
    }
    float rv[4];
    float* Rb = Rout + (size_t)b * IMH * IMW + (size_t)y0 * IMW + x0;
    #pragma unroll
    for (int j = 0; j < 4; ++j) {
        float sxx = 0.f, syy = 0.f, sxy = 0.f;
        #pragma unroll
        for (int d = 0; d < 7; ++d) {
            sxx += a[d] * vxx[j + d];
            syy += a[d] * vyy[j + d];
            sxy += a[d] * vxy[j + d];
        }
        float tr = sxx + syy;
        float R = sxx * syy - sxy * sxy - 0.05f * tr * tr;
        rv[j] = R;
        Rb[(size_t)(4 * ty + j) * IMW + tx] = R;
    }
    __syncthreads();   // LH zeroing complete

    #pragma unroll
    for (int j = 0; j < 4; ++j) atomicAdd(&LH[f2u(rv[j]) >> 20], 1u);
    __syncthreads();

    const unsigned slot = ((blockIdx.z * gridDim.y + blockIdx.y) * gridDim.x + blockIdx.x) & 7u;
    for (int i = tid; i < 4096; i += 512) {
        unsigned c = LH[i];
        if (c) atomicAdd(&hist[i * 8 + slot], c);
    }
}

// ---------- median: radix select; pass 1 fused above (8-slot striped) ----------
__global__ void zero_kernel(unsigned* __restrict__ p, int n, int kidx, unsigned kval) {
    int i = blockIdx.x * blockDim.x + threadIdx.x;
    if (i < n) p[i] = (i == kidx) ? kval : 0u;
}

__global__ void hist2_kernel(const float* __restrict__ R, unsigned* __restrict__ hist,
                             const unsigned* __restrict__ sel) {
    __shared__ unsigned lh[4096];
    for (int i = threadIdx.x; i < 4096; i += 256) lh[i] = 0u;
    __syncthreads();
    const unsigned pref = sel[1];
    const float4* R4 = (const float4*)R;
    const int n4 = NPIX / 4;
    for (int i = blockIdx.x * 256 + threadIdx.x; i < n4; i += gridDim.x * 256) {
        float4 v = R4[i];
        unsigned u;
        u = f2u(v.x); if ((u >> 20) == pref) atomicAdd(&lh[(u >> 8) & 0xFFFu], 1u);
        u = f2u(v.y); if ((u >> 20) == pref) atomicAdd(&lh[(u >> 8) & 0xFFFu], 1u);
        u = f2u(v.z); if ((u >> 20) == pref) atomicAdd(&lh[(u >> 8) & 0xFFFu], 1u);
        u = f2u(v.w); if ((u >> 20) == pref) atomicAdd(&lh[(u >> 8) & 0xFFFu], 1u);
    }
    __syncthreads();
    for (int i = threadIdx.x; i < 4096; i += 256) { unsigned c = lh[i]; if (c) atomicAdd(&hist[i], c); }
}

__global__ void hist3_kernel(const float* __restrict__ R, unsigned* __restrict__ hist,
                             const unsigned* __restrict__ sel) {
    __shared__ unsigned lh[256];
    if (threadIdx.x < 256) lh[threadIdx.x] = 0u;
    __syncthreads();
    const unsigned pref = sel[1];
    const float4* R4 = (const float4*)R;
    const int n4 = NPIX / 4;
    for (int i = blockIdx.x * 256 + threadIdx.x; i < n4; i += gridDim.x * 256) {
        float4 v = R4[i];
        unsigned u;
        u = f2u(v.x); if ((u >> 8) == pref) atomicAdd(&lh[u & 0xFFu], 1u);
        u = f2u(v.y); if ((u >> 8) == pref) atomicAdd(&lh[u & 0xFFu], 1u);
        u = f2u(v.z); if ((u >> 8) == pref) atomicAdd(&lh[u & 0xFFu], 1u);
        u = f2u(v.w); if ((u >> 8) == pref) atomicAdd(&lh[u & 0xFFu], 1u);
    }
    __syncthreads();
    { unsigned c = lh[threadIdx.x]; if (c) atomicAdd(&hist[threadIdx.x], c); }
}

__global__ void select_kernel(const unsigned* __restrict__ hist, unsigned* __restrict__ sel,
                              int bpt, int bits, int final_stage, int slots) {
    __shared__ unsigned part[256];
    __shared__ unsigned grp[16];
    __shared__ int chs;
    __shared__ unsigned runs;
    const int t = threadIdx.x;
    const unsigned krem = sel[0];
    unsigned s = 0;
    for (int i = 0; i < bpt; ++i) {
        unsigned bsum = 0;
        for (int j = 0; j < slots; ++j) bsum += hist[(t * bpt + i) * slots + j];
        s += bsum;
    }
    part[t] = s;
    __syncthreads();
    #pragma unroll
    for (int off = 1; off < 256; off <<= 1) {
        unsigned add = (t >= off) ? part[t - off] : 0u;
        __syncthreads();
        part[t] += add;
        __syncthreads();
    }
    unsigned incl = part[t];
    unsigned excl = incl - s;
    if (excl <= krem && krem < incl) { chs = t; runs = excl; }
    __syncthreads();
    int ch = chs;
    if (t < bpt) {
        unsigned g = 0;
        for (int j = 0; j < slots; ++j) g += hist[(ch * bpt + t) * slots + j];
        grp[t] = g;
    }
    __syncthreads();
    if (t == 0) {
        unsigned r2 = runs; int bsel = ch * bpt;
        for (int j = 0; j < bpt; ++j) {
            unsigned h = grp[j];
            if (r2 + h > krem) { bsel = ch * bpt + j; break; }
            r2 += h;
        }
        sel[0] = krem - r2;
        unsigned pref = (sel[1] << bits) | (unsigned)bsel;
        sel[1] = pref;
        if (final_stage) {
            unsigned fb = (pref & 0x80000000u) ? (pref ^ 0x80000000u) : ~pref;
            ((float*)sel)[2] = __uint_as_float(fb);
        }
    }
}

// ---------- K2: threshold + 7x7 maxpool + binarize*R, tile 64x64, 512 threads ----------
__launch_bounds__(512, 6)
__global__ void harris_out(const float* __restrict__ R, const unsigned* __restrict__ sel,
                           float* __restrict__ out) {
    __shared__ __align__(16) float smem2[9520];   // 38080 B
    float* SR = smem2;                            // [70*72] raw R halo 3, OOB=-inf
    float2* SM2 = (float2*)(smem2 + 5040);        // [70*32] horizontal thr-max col pairs
    const float med = ((const float*)sel)[2];
    const int tid = threadIdx.x;
    const int x0 = blockIdx.x * 64, y0 = blockIdx.y * 64, b = blockIdx.z;
    const float* Rb = R + (size_t)b * IMH * IMW;

    for (int i = tid; i < 70 * 70; i += 512) {
        int r = i / 70, c = i - r * 70;
        int gy = y0 - 3 + r, gx = x0 - 3 + c;
        float v = -INFINITY;
        if ((unsigned)gy < (unsigned)IMH && (unsigned)gx < (unsigned)IMW)
            v = Rb[(size_t)gy * IMW + gx];
        SR[r * 72 + c] = v;
    }
    __syncthreads();

    // h-max over thresholded values: 70 rows x 32 pairs (max reassoc is exact)
    for (int i = tid; i < 70 * 32; i += 512) {
        int r = i >> 5, p = i & 31;
        const float2* u = (const float2*)(SR + r * 72 + 2 * p);
        float2 u0 = u[0], u1 = u[1], u2 = u[2], u3 = u[3];
        float cv[8] = {u0.x, u0.y, u1.x, u1.y, u2.x, u2.y, u3.x, u3.y};
        float tv[8];
        #pragma unroll
        for (int k = 0; k < 8; ++k) {
            float v = cv[k];
            tv[k] = (v < med) ? ((v == -INFINITY) ? -INFINITY : 0.0f) : v;
        }
        float mid = fmaxf(fmaxf(fmaxf(tv[1], tv[2]), fmaxf(tv[3], tv[4])), fmaxf(tv[5], tv[6]));
        SM2[r * 32 + p] = make_float2(fmaxf(tv[0], mid), fmaxf(tv[7], mid));
    }
    __syncthreads();

    // v-max (f2 tree) + binarize: thread = (pair p, rowgroup g of 4 rows)
    const int p = tid & 31, g = tid >> 5;     // g in 0..15
    float2 vm[10];
    #pragma unroll
    for (int t = 0; t < 10; ++t) vm[t] = SM2[(4 * g + t) * 32 + p];
    float2 m2[9];
    #pragma unroll
    for (int i = 0; i < 9; ++i) m2[i] = fmax2(vm[i], vm[i + 1]);
    float2 m4[7];
    #pragma unroll
    for (int i = 0; i < 7; ++i) m4[i] = fmax2(m2[i], m2[i + 2]);
    float* ob = out + (size_t)b * IMH * IMW + (size_t)y0 * IMW + x0;
    #pragma unroll
    for (int j = 0; j < 4; ++j) {
        float2 pooled = fmax2(m4[j], m4[j + 3]);
        float vA = SR[(4 * g + j + 3) * 72 + 2 * p + 3];
        float vB = SR[(4 * g + j + 3) * 72 + 2 * p + 4];
        float tA = (vA < med) ? 0.0f : vA;
        float tB = (vB < med) ? 0.0f : vB;
        float2 o = make_float2((tA == pooled.x) ? vA : 0.0f, (tB == pooled.y) ? vB : 0.0f);
        *(float2*)&ob[(size_t)(4 * g + j) * IMW + 2 * p] = o;
    }
}

extern "C" void kernel_launch(void* const* d_in, const int* in_sizes, int n_in,
                              void* d_out, int out_size, void* d_ws, size_t ws_size,
                              hipStream_t stream) {
    const float* x = (const float*)d_in[0];
    float* out = (float*)d_out;

    // ws: R (64MB) | h1[4096*8] | h2[4096] | h3[256] | sel[8]
    const size_t needed = (size_t)NPIX * 4 + (32768 + 4096 + 256 + 8) * 4;
    if (ws_size < needed) return;
    float* R = (float*)d_ws;
    unsigned* hbase = (unsigned*)((char*)d_ws + (size_t)NPIX * 4);
    unsigned* h1 = hbase;            // 32768 (4096 bins x 8 slots)
    unsigned* h2 = hbase + 32768;    // 4096
    unsigned* h3 = hbase + 36864;    // 256
    unsigned* sel = hbase + 37120;   // 8

    zero_kernel<<<(37128 + 255) / 256, 256, 0, stream>>>(hbase, 37128, 37120, KSEL);

    dim3 rgrid(IMW / 64, IMH / 32, NB);
    harris_R<<<rgrid, 512, 0, stream>>>(x, R, h1);

    select_kernel<<<1, 256, 0, stream>>>(h1, sel, 16, 12, 0, 8);
    hist2_kernel<<<2048, 256, 0, stream>>>(R, h2, sel);
    select_kernel<<<1, 256, 0, stream>>>(h2, sel, 16, 12, 0, 1);
    hist3_kernel<<<2048, 256, 0, stream>>>(R, h3, sel);
    select_kernel<<<1, 256, 0, stream>>>(h3, sel, 1, 8, 1, 1);

    dim3 ogrid(IMW / 64, IMH / 64, NB);
    harris_out<<<ogrid, 512, 0, stream>>>(R, sel, out);
}